// Round 1
// baseline (4223.535 us; speedup 1.0000x reference)
//
#include <hip/hip_runtime.h>
#include <hip/hip_bf16.h>
#include <math.h>

// Problem constants
#define NB   256      // batch
#define ML   31       // MAX_LEN
#define NT   30       // T = MAX_LEN-1 decode steps
#define NV   10000    // vocab
#define NH   512      // hidden
#define NE   512      // embed
#define NG   2048     // 4*H gates

// Output layout (floats): preds (256,31,10000) | target (256,30) | dec_len (256,)
#define OFF_TGT  (256LL*31LL*10000LL)        // 79,360,000
#define OFF_DEC  (OFF_TGT + 256LL*30LL)      // 79,367,680
#define PRED_B   (31LL*10000LL)              // 310,000 per-batch stride

// ---------------- sort: stable descending argsort of caption_lengths ----------
__global__ void sort_k(const int* __restrict__ lens, int* __restrict__ order,
                       int* __restrict__ declen, float* __restrict__ out_dec) {
    int i = threadIdx.x;
    int li = lens[i];
    int r = 0;
    for (int j = 0; j < NB; j++) {
        int lj = lens[j];
        r += (lj > li) || (lj == li && j < i);
    }
    order[r] = i;
    declen[r] = li - 1;
    out_dec[r] = (float)(li - 1);
}

// ---------------- gather sorted rows, zero h/c, emit target -------------------
__global__ void gather_k(const float* __restrict__ gimg, const int* __restrict__ w_in,
                         const int* __restrict__ order,
                         float* __restrict__ g_s, int* __restrict__ wsort,
                         float* __restrict__ h, float* __restrict__ c,
                         float* __restrict__ out_tgt) {
    int r = blockIdx.x, tid = threadIdx.x;
    int o = order[r];
    for (int e = tid; e < NE; e += 256) {
        g_s[r * NE + e] = gimg[o * NE + e];
        h[r * NH + e] = 0.f;
        c[r * NH + e] = 0.f;
    }
    if (tid < ML) wsort[r * ML + tid] = w_in[o * ML + tid];
    if (tid < NT) out_tgt[r * NT + tid] = (float)w_in[o * ML + tid + 1];
}

// ---------------- Wcat[j][k] = k<512 ? W_ih[j][512+k] : W_hh[j][k-512] --------
__global__ void wcat_k(const float* __restrict__ W_ih, const float* __restrict__ W_hh,
                       float* __restrict__ Wcat) {
    int gid = blockIdx.x * 256 + threadIdx.x;   // 2048*1024
    int j = gid >> 10, k = gid & 1023;
    Wcat[gid] = (k < NE) ? W_ih[j * (2 * NE) + NE + k] : W_hh[j * NH + (k - NE)];
}

// ---------------- zero pad column preds[:,30,:] -------------------------------
__global__ void pad_k(float* __restrict__ out) {
    int gid = blockIdx.x * 256 + threadIdx.x;   // 256*10000
    if (gid < NB * NV) {
        int b = gid / NV, v = gid % NV;
        out[(size_t)b * PRED_B + (size_t)NT * NV + v] = 0.f;
    }
}

// ---------------- generic fp32 GEMM: C = A @ B^T (+bias, +epilogues) ----------
// A: M x K row-major (or AMODE==1: concat[emb[w_t]|h] built on the fly)
// B: N x K row-major (ldb row stride)
// AMODE 0: plain A.  AMODE 1: k<512 -> emb[wsort[b*31+t]][k], else h[b][k-512]
// EPI 0: C[m*ldc+n] = v (+bias1+bias2)
// EPI 1: C[m*ldc+n] = v + addm[m*ldc+n]
// EPI 2: scatter logits: C[(m&255)*310000 + (m>>8)*10000 + n] = v + bias1[n]
template <int AMODE, int EPI>
__launch_bounds__(256)
__global__ void gemm_k(const float* __restrict__ A, int lda,
                       const float* __restrict__ Bm, int ldb,
                       float* __restrict__ C, int ldc,
                       int M, int N, int K,
                       const float* __restrict__ bias1,
                       const float* __restrict__ bias2,
                       const float* __restrict__ addm,
                       const int* __restrict__ wsort,
                       const float* __restrict__ emb,
                       const float* __restrict__ hbuf,
                       int tstep) {
    __shared__ __align__(16) float As[16][68];
    __shared__ __align__(16) float Bs[16][68];
    int tid = threadIdx.x;
    int tx = tid & 15, ty = tid >> 4;
    int m0 = blockIdx.y * 64, n0 = blockIdx.x * 64;
    int lrow = tid >> 2;        // 0..63
    int lk = (tid & 3) * 4;     // 0,4,8,12

    float acc[4][4];
#pragma unroll
    for (int i = 0; i < 4; i++)
#pragma unroll
        for (int j = 0; j < 4; j++) acc[i][j] = 0.f;

    for (int k0 = 0; k0 < K; k0 += 16) {
        // load A 64x16 tile
        float4 av;
        if (AMODE == 0) {
            av = *(const float4*)(A + (size_t)(m0 + lrow) * lda + k0 + lk);
        } else {
            int k = k0 + lk;
            int b = m0 + lrow;
            if (k < NE) {
                int idx = wsort[b * ML + tstep];
                av = *(const float4*)(emb + (size_t)idx * NE + k);
            } else {
                av = *(const float4*)(hbuf + (size_t)b * NH + (k - NE));
            }
        }
        // load B 64x16 tile (bounds on N)
        float4 bv = make_float4(0.f, 0.f, 0.f, 0.f);
        {
            int n = n0 + lrow;
            if (n < N) bv = *(const float4*)(Bm + (size_t)n * ldb + k0 + lk);
        }
        As[lk + 0][lrow] = av.x; As[lk + 1][lrow] = av.y;
        As[lk + 2][lrow] = av.z; As[lk + 3][lrow] = av.w;
        Bs[lk + 0][lrow] = bv.x; Bs[lk + 1][lrow] = bv.y;
        Bs[lk + 2][lrow] = bv.z; Bs[lk + 3][lrow] = bv.w;
        __syncthreads();
#pragma unroll
        for (int kk = 0; kk < 16; kk++) {
            float4 a4 = *(const float4*)&As[kk][ty * 4];
            float4 b4 = *(const float4*)&Bs[kk][tx * 4];
            float ar[4] = {a4.x, a4.y, a4.z, a4.w};
            float br[4] = {b4.x, b4.y, b4.z, b4.w};
#pragma unroll
            for (int i = 0; i < 4; i++)
#pragma unroll
                for (int j = 0; j < 4; j++) acc[i][j] = fmaf(ar[i], br[j], acc[i][j]);
        }
        __syncthreads();
    }

#pragma unroll
    for (int i = 0; i < 4; i++) {
        int m = m0 + ty * 4 + i;
#pragma unroll
        for (int j = 0; j < 4; j++) {
            int n = n0 + tx * 4 + j;
            if (n >= N) continue;
            float v = acc[i][j];
            if (bias1) v += bias1[n];
            if (bias2) v += bias2[n];
            if (EPI == 1) v += addm[(size_t)m * ldc + n];
            if (EPI == 2) {
                int b = m & 255, t = m >> 8;
                C[(size_t)b * PRED_B + (size_t)t * NV + n] = v;
            } else {
                C[(size_t)m * ldc + n] = v;
            }
        }
    }
}

// ---------------- LSTM cell elementwise --------------------------------------
__global__ void lstm_cell(const float* __restrict__ gates, float* __restrict__ h,
                          float* __restrict__ c, float* __restrict__ h_all,
                          const int* __restrict__ declen, int t) {
    int gid = blockIdx.x * 256 + threadIdx.x;   // 256*512
    int b = gid >> 9;
    int hh = gid & 511;
    const float* gr = gates + (size_t)b * NG;
    float ig = gr[hh], fg = gr[NH + hh], gg = gr[2 * NH + hh], og = gr[3 * NH + hh];
    float i_ = 1.f / (1.f + expf(-ig));
    float f_ = 1.f / (1.f + expf(-fg));
    float o_ = 1.f / (1.f + expf(-og));
    float g_ = tanhf(gg);
    float cold = c[gid], hold = h[gid];
    float cn = f_ * cold + i_ * g_;
    float hn = o_ * tanhf(cn);
    bool act = t < declen[b];
    h[gid] = act ? hn : hold;
    c[gid] = act ? cn : cold;
    h_all[(size_t)t * (NB * NH) + gid] = hn;   // rows r = t*256+b
}

// ---------------- in-place log_softmax over V, zero inactive rows -------------
__global__ void lsm_k(float* __restrict__ out, const int* __restrict__ declen) {
    int r = blockIdx.x;         // 0..7679, r = t*256+b
    int t = r >> 8, b = r & 255;
    float* row = out + (size_t)b * PRED_B + (size_t)t * NV;
    __shared__ float red[256];
    int tid = threadIdx.x;
    float m = -1e30f;
    for (int v = tid; v < NV; v += 256) m = fmaxf(m, row[v]);
    red[tid] = m; __syncthreads();
    for (int s = 128; s > 0; s >>= 1) {
        if (tid < s) red[tid] = fmaxf(red[tid], red[tid + s]);
        __syncthreads();
    }
    m = red[0]; __syncthreads();
    float sum = 0.f;
    for (int v = tid; v < NV; v += 256) sum += expf(row[v] - m);
    red[tid] = sum; __syncthreads();
    for (int s = 128; s > 0; s >>= 1) {
        if (tid < s) red[tid] += red[tid + s];
        __syncthreads();
    }
    float lse = logf(red[0]);
    bool act = t < declen[b];
    for (int v = tid; v < NV; v += 256) row[v] = act ? (row[v] - m - lse) : 0.f;
}

extern "C" void kernel_launch(void* const* d_in, const int* in_sizes, int n_in,
                              void* d_out, int out_size, void* d_ws, size_t ws_size,
                              hipStream_t stream) {
    const float* gimg  = (const float*)d_in[0];
    const int*   w_in  = (const int*)d_in[1];
    const int*   lens  = (const int*)d_in[2];
    const float* emb   = (const float*)d_in[3];
    const float* W_ih  = (const float*)d_in[4];
    const float* W_hh  = (const float*)d_in[5];
    const float* b_ih  = (const float*)d_in[6];
    const float* b_hh  = (const float*)d_in[7];
    const float* W_out = (const float*)d_in[8];
    const float* b_out = (const float*)d_in[9];
    float* out = (float*)d_out;

    char* p = (char*)d_ws;
    auto alloc = [&](size_t bytes) -> char* {
        char* r = p;
        p += (bytes + 255) & ~(size_t)255;
        return r;
    };
    int*   order  = (int*)alloc(NB * 4);
    int*   wsort  = (int*)alloc(NB * ML * 4);
    int*   declen = (int*)alloc(NB * 4);
    float* g_s    = (float*)alloc((size_t)NB * NE * 4);
    float* gx     = (float*)alloc((size_t)NB * NG * 4);
    float* Wcat   = (float*)alloc((size_t)NG * 1024 * 4);
    float* h      = (float*)alloc((size_t)NB * NH * 4);
    float* c      = (float*)alloc((size_t)NB * NH * 4);
    float* gates  = (float*)alloc((size_t)NB * NG * 4);
    float* h_all  = (float*)alloc((size_t)NT * NB * NH * 4);

    sort_k<<<1, 256, 0, stream>>>(lens, order, declen, out + OFF_DEC);
    gather_k<<<NB, 256, 0, stream>>>(gimg, w_in, order, g_s, wsort, h, c, out + OFF_TGT);
    wcat_k<<<(NG * 1024) / 256, 256, 0, stream>>>(W_ih, W_hh, Wcat);
    pad_k<<<(NB * NV + 255) / 256, 256, 0, stream>>>(out);

    // gx = g_s @ W_ih[:, :512]^T + b_ih + b_hh      (256 x 2048, K=512)
    gemm_k<0, 0><<<dim3(2048 / 64, 256 / 64), 256, 0, stream>>>(
        g_s, NE, W_ih, 2 * NE, gx, NG, NB, NG, NE,
        b_ih, b_hh, nullptr, nullptr, nullptr, nullptr, 0);

    for (int t = 0; t < NT; t++) {
        // gates = gx + [emb[w_t] | h] @ Wcat^T      (256 x 2048, K=1024)
        gemm_k<1, 1><<<dim3(2048 / 64, 256 / 64), 256, 0, stream>>>(
            nullptr, 0, Wcat, 1024, gates, NG, NB, NG, 1024,
            nullptr, nullptr, gx, wsort, emb, h, t);
        lstm_cell<<<(NB * NH) / 256, 256, 0, stream>>>(gates, h, c, h_all, declen, t);
    }

    // logits = h_all @ W_out^T + b_out, scattered to preds[b][t][:]   (7680 x 10000, K=512)
    gemm_k<0, 2><<<dim3((NV + 63) / 64, (NT * NB) / 64), 256, 0, stream>>>(
        h_all, NH, W_out, NH, out, 0, NT * NB, NV, NH,
        b_out, nullptr, nullptr, nullptr, nullptr, nullptr, 0);

    lsm_k<<<NT * NB, 256, 0, stream>>>(out, declen);
}

// Round 2
// 1922.360 us; speedup vs baseline: 2.1971x; 2.1971x over previous
//
#include <hip/hip_runtime.h>
#include <hip/hip_bf16.h>
#include <math.h>

// Problem constants
#define NB   256      // batch
#define ML   31       // MAX_LEN
#define NT   30       // T = MAX_LEN-1 decode steps
#define NV   10000    // vocab
#define NH   512      // hidden
#define NE   512      // embed
#define NG   2048     // 4*H gates

// Output layout (floats): preds (256,31,10000) | target (256,30) | dec_len (256,)
#define OFF_TGT  (256LL*31LL*10000LL)
#define OFF_DEC  (OFF_TGT + 256LL*30LL)
#define PRED_B   (31LL*10000LL)

typedef __attribute__((ext_vector_type(8))) short bf16x8;
typedef __attribute__((ext_vector_type(4))) float f32x4;

__device__ inline unsigned short f2bf(float f) {
    unsigned int x = __float_as_uint(f);
    unsigned int r = x + 0x7FFFu + ((x >> 16) & 1u);   // RNE
    return (unsigned short)(r >> 16);
}
__device__ inline float bf2f(unsigned short u) {
    return __uint_as_float((unsigned int)u << 16);
}

// ---------------- sort: stable descending argsort of caption_lengths ----------
__global__ void sort_k(const int* __restrict__ lens, int* __restrict__ order,
                       int* __restrict__ declen, float* __restrict__ out_dec) {
    int i = threadIdx.x;
    int li = lens[i];
    int r = 0;
    for (int j = 0; j < NB; j++) {
        int lj = lens[j];
        r += (lj > li) || (lj == li && j < i);
    }
    order[r] = i;
    declen[r] = li - 1;
    out_dec[r] = (float)(li - 1);
}

// ---------------- gather sorted rows, zero h/c/hb, emit target ----------------
__global__ void gather_k(const float* __restrict__ gimg, const int* __restrict__ w_in,
                         const int* __restrict__ order,
                         float* __restrict__ g_s, int* __restrict__ wsort,
                         float* __restrict__ h, float* __restrict__ c,
                         unsigned short* __restrict__ hb,
                         float* __restrict__ out_tgt) {
    int r = blockIdx.x, tid = threadIdx.x;
    int o = order[r];
    for (int e = tid; e < NE; e += 256) {
        g_s[r * NE + e] = gimg[o * NE + e];
        h[r * NH + e] = 0.f;
        c[r * NH + e] = 0.f;
        hb[r * NH + e] = 0;
    }
    if (tid < ML) wsort[r * ML + tid] = w_in[o * ML + tid];
    if (tid < NT) out_tgt[r * NT + tid] = (float)w_in[o * ML + tid + 1];
}

// ---------------- rowword[r] = wsort[(r&255)][r>>8] ---------------------------
__global__ void rw_k(const int* __restrict__ wsort, int* __restrict__ rowword) {
    int r = blockIdx.x * 256 + threadIdx.x;
    if (r < NT * NB) rowword[r] = wsort[(r & 255) * ML + (r >> 8)];
}

// ---------------- fp32 -> bf16 conversions ------------------------------------
__global__ void f2b_k(const float* __restrict__ src, unsigned short* __restrict__ dst, int n4) {
    int i = blockIdx.x * 256 + threadIdx.x;
    if (i >= n4) return;
    float4 v = ((const float4*)src)[i];
    ushort4 o;
    o.x = f2bf(v.x); o.y = f2bf(v.y); o.z = f2bf(v.z); o.w = f2bf(v.w);
    ((ushort4*)dst)[i] = o;
}

// Wxb[j][k] = bf16(W_ih[j][512+k])
__global__ void wxb_k(const float* __restrict__ W_ih, unsigned short* __restrict__ Wxb) {
    int gid = blockIdx.x * 256 + threadIdx.x;   // 2048*128 float4 chunks
    int j = gid >> 7, k4 = gid & 127;
    float4 v = *(const float4*)(W_ih + (size_t)j * (2 * NE) + NE + k4 * 4);
    ushort4 o;
    o.x = f2bf(v.x); o.y = f2bf(v.y); o.z = f2bf(v.z); o.w = f2bf(v.w);
    *(ushort4*)(Wxb + (size_t)j * NE + k4 * 4) = o;
}

// ---------------- zero pad column preds[:,30,:] + zero rowsum -----------------
__global__ void pad_k(float* __restrict__ out) {
    int gid = blockIdx.x * 256 + threadIdx.x;
    if (gid < NB * NV) {
        int b = gid / NV, v = gid % NV;
        out[(size_t)b * PRED_B + (size_t)NT * NV + v] = 0.f;
    }
}
__global__ void zero_k(float* __restrict__ p, int n) {
    int i = blockIdx.x * 256 + threadIdx.x;
    if (i < n) p[i] = 0.f;
}

// ---------------- fp32 GEMM for gx = g_s @ W_ih_left^T + b_ih + b_hh ----------
__launch_bounds__(256)
__global__ void gxgemm_k(const float* __restrict__ A, const float* __restrict__ Bm,
                         float* __restrict__ C,
                         const float* __restrict__ bias1, const float* __restrict__ bias2) {
    // M=256 N=2048 K=512, lda=512 ldb=1024 ldc=2048, 64x64 tile
    __shared__ __align__(16) float As[16][68];
    __shared__ __align__(16) float Bs[16][68];
    int tid = threadIdx.x;
    int tx = tid & 15, ty = tid >> 4;
    int m0 = blockIdx.y * 64, n0 = blockIdx.x * 64;
    int lrow = tid >> 2;
    int lk = (tid & 3) * 4;
    float acc[4][4];
#pragma unroll
    for (int i = 0; i < 4; i++)
#pragma unroll
        for (int j = 0; j < 4; j++) acc[i][j] = 0.f;
    for (int k0 = 0; k0 < NE; k0 += 16) {
        float4 av = *(const float4*)(A + (size_t)(m0 + lrow) * NE + k0 + lk);
        float4 bv = *(const float4*)(Bm + (size_t)(n0 + lrow) * (2 * NE) + k0 + lk);
        As[lk + 0][lrow] = av.x; As[lk + 1][lrow] = av.y;
        As[lk + 2][lrow] = av.z; As[lk + 3][lrow] = av.w;
        Bs[lk + 0][lrow] = bv.x; Bs[lk + 1][lrow] = bv.y;
        Bs[lk + 2][lrow] = bv.z; Bs[lk + 3][lrow] = bv.w;
        __syncthreads();
#pragma unroll
        for (int kk = 0; kk < 16; kk++) {
            float4 a4 = *(const float4*)&As[kk][ty * 4];
            float4 b4 = *(const float4*)&Bs[kk][tx * 4];
            float ar[4] = {a4.x, a4.y, a4.z, a4.w};
            float br[4] = {b4.x, b4.y, b4.z, b4.w};
#pragma unroll
            for (int i = 0; i < 4; i++)
#pragma unroll
                for (int j = 0; j < 4; j++) acc[i][j] = fmaf(ar[i], br[j], acc[i][j]);
        }
        __syncthreads();
    }
#pragma unroll
    for (int i = 0; i < 4; i++) {
        int m = m0 + ty * 4 + i;
#pragma unroll
        for (int j = 0; j < 4; j++) {
            int n = n0 + tx * 4 + j;
            C[(size_t)m * NG + n] = acc[i][j] + bias1[n] + bias2[n];
        }
    }
}

// ---------------- bf16 MFMA GEMM: C = A(bf16,MxK=512) @ B(bf16,NxK=512)^T -----
// Tile 128x128, 4 waves (2x2), wave tile 64x64 (4x4 frags of 16x16), BK=64.
// AMODE 0: A rows from Abf.  AMODE 1: A row r = embb + rowword[r]*512.
// EPI 0: outb[m*2048+n] = bf16(acc)                        (Xemb -> gallb)
// EPI 1: v=acc+bout[n]; preds scatter + rowsum exp-atomics  (big output GEMM)
// EPI 2: outf[m*2048+n] = acc + addf[m*2048+n] + bf2f(addb[m*2048+n])  (gates)
template <int AMODE, int EPI>
__launch_bounds__(256)
__global__ void mfgemm(const unsigned short* __restrict__ Abf,
                       const int* __restrict__ rowword,
                       const unsigned short* __restrict__ embb,
                       const unsigned short* __restrict__ Bbf,
                       int N,
                       const float* __restrict__ addf,
                       const unsigned short* __restrict__ addb,
                       const float* __restrict__ bout,
                       float* __restrict__ outf,
                       unsigned short* __restrict__ outb,
                       float* __restrict__ rowsum) {
    __shared__ __align__(16) char lds[32768];
    char* Alds = lds;            // [128 rows][64 k] bf16, XOR-swizzled
    char* Blds = lds + 16384;
    int tid = threadIdx.x;
    int wave = tid >> 6, lane = tid & 63;
    int wy = wave >> 1, wx = wave & 1;
    int m0 = blockIdx.y * 128, n0 = blockIdx.x * 128;
    int srow = tid >> 3;        // 0..31
    int schunk = tid & 7;       // 16B chunk (8 bf16)

    f32x4 acc[4][4];
#pragma unroll
    for (int i = 0; i < 4; i++)
#pragma unroll
        for (int j = 0; j < 4; j++) acc[i][j] = (f32x4){0.f, 0.f, 0.f, 0.f};

    uint4 areg[4], breg[4];
    auto load_tile = [&](int kt) {
        int k0 = kt * 64;
#pragma unroll
        for (int p = 0; p < 4; ++p) {
            int row = p * 32 + srow;
            const unsigned short* ap;
            if (AMODE == 0) ap = Abf + ((size_t)(m0 + row) << 9);
            else            ap = embb + ((size_t)rowword[m0 + row] << 9);
            areg[p] = *(const uint4*)(ap + k0 + (schunk << 3));
            int n = n0 + row;
            if (n < N) breg[p] = *(const uint4*)(Bbf + ((size_t)n << 9) + k0 + (schunk << 3));
            else       breg[p] = make_uint4(0u, 0u, 0u, 0u);
        }
    };

    load_tile(0);
    for (int kt = 0; kt < 8; ++kt) {
        __syncthreads();
#pragma unroll
        for (int p = 0; p < 4; ++p) {
            int row = p * 32 + srow;
            int ba = (row << 7) + (schunk << 4); ba ^= (row & 7) << 4;
            *(uint4*)(Alds + ba) = areg[p];
            *(uint4*)(Blds + ba) = breg[p];
        }
        __syncthreads();
        if (kt < 7) load_tile(kt + 1);
#pragma unroll
        for (int kc = 0; kc < 2; ++kc) {
            bf16x8 aq[4], bq[4];
#pragma unroll
            for (int i = 0; i < 4; ++i) {
                int row = (wy << 6) + (i << 4) + (lane & 15);
                int kk = (kc << 5) + ((lane >> 4) << 3);
                int ba = (row << 7) + (kk << 1); ba ^= (row & 7) << 4;
                aq[i] = *(const bf16x8*)(Alds + ba);
                int col = (wx << 6) + (i << 4) + (lane & 15);
                int bb = (col << 7) + (kk << 1); bb ^= (col & 7) << 4;
                bq[i] = *(const bf16x8*)(Blds + bb);
            }
#pragma unroll
            for (int i = 0; i < 4; ++i)
#pragma unroll
                for (int j = 0; j < 4; ++j)
                    acc[i][j] = __builtin_amdgcn_mfma_f32_16x16x32_bf16(aq[i], bq[j], acc[i][j], 0, 0, 0);
        }
    }

    // Epilogue.  D frag mapping: col = lane&15, row = (lane>>4)*4 + r.
    if (EPI == 0) {
#pragma unroll
        for (int i = 0; i < 4; ++i)
#pragma unroll
            for (int j = 0; j < 4; ++j) {
                int n = n0 + (wx << 6) + (j << 4) + (lane & 15);
#pragma unroll
                for (int r = 0; r < 4; ++r) {
                    int m = m0 + (wy << 6) + (i << 4) + ((lane >> 4) << 2) + r;
                    outb[(size_t)m * NG + n] = f2bf(acc[i][j][r]);
                }
            }
    } else if (EPI == 2) {
#pragma unroll
        for (int i = 0; i < 4; ++i)
#pragma unroll
            for (int j = 0; j < 4; ++j) {
                int n = n0 + (wx << 6) + (j << 4) + (lane & 15);
#pragma unroll
                for (int r = 0; r < 4; ++r) {
                    int m = m0 + (wy << 6) + (i << 4) + ((lane >> 4) << 2) + r;
                    size_t idx = (size_t)m * NG + n;
                    outf[idx] = acc[i][j][r] + addf[idx] + bf2f(addb[idx]);
                }
            }
    } else {
        float es[4][4];
#pragma unroll
        for (int i = 0; i < 4; ++i)
#pragma unroll
            for (int r = 0; r < 4; ++r) es[i][r] = 0.f;
#pragma unroll
        for (int i = 0; i < 4; ++i)
#pragma unroll
            for (int j = 0; j < 4; ++j) {
                int n = n0 + (wx << 6) + (j << 4) + (lane & 15);
                bool ok = n < N;
                float bo = ok ? bout[n] : 0.f;
#pragma unroll
                for (int r = 0; r < 4; ++r) {
                    int m = m0 + (wy << 6) + (i << 4) + ((lane >> 4) << 2) + r;
                    float v = acc[i][j][r] + bo;
                    if (ok) {
                        outf[(size_t)(m & 255) * PRED_B + (size_t)(m >> 8) * NV + n] = v;
                        es[i][r] += expf(v);
                    }
                }
            }
#pragma unroll
        for (int i = 0; i < 4; ++i)
#pragma unroll
            for (int r = 0; r < 4; ++r) {
                float s = es[i][r];
                s += __shfl_xor(s, 1); s += __shfl_xor(s, 2);
                s += __shfl_xor(s, 4); s += __shfl_xor(s, 8);
                if ((lane & 15) == 0) {
                    int m = m0 + (wy << 6) + (i << 4) + ((lane >> 4) << 2) + r;
                    atomicAdd(&rowsum[m], s);
                }
            }
    }
}

// ---------------- LSTM cell elementwise --------------------------------------
__global__ void lstm_cell(const float* __restrict__ gates, float* __restrict__ h,
                          float* __restrict__ c, unsigned short* __restrict__ hb,
                          unsigned short* __restrict__ h_allb,
                          const int* __restrict__ declen, int t) {
    int gid = blockIdx.x * 256 + threadIdx.x;   // 256*512
    int b = gid >> 9;
    int hh = gid & 511;
    const float* gr = gates + (size_t)b * NG;
    float ig = gr[hh], fg = gr[NH + hh], gg = gr[2 * NH + hh], og = gr[3 * NH + hh];
    float i_ = 1.f / (1.f + expf(-ig));
    float f_ = 1.f / (1.f + expf(-fg));
    float o_ = 1.f / (1.f + expf(-og));
    float g_ = tanhf(gg);
    float cold = c[gid], hold = h[gid];
    float cn = f_ * cold + i_ * g_;
    float hn = o_ * tanhf(cn);
    bool act = t < declen[b];
    float hkeep = act ? hn : hold;
    h[gid] = hkeep;
    c[gid] = act ? cn : cold;
    hb[gid] = f2bf(hkeep);
    h_allb[(size_t)t * (NB * NH) + gid] = f2bf(hn);   // rows r = t*256+b
}

// ---------------- final pass: preds = logit - log(rowsum), zero inactive ------
__global__ void norm_k(float* __restrict__ out, const float* __restrict__ rowsum,
                       const int* __restrict__ declen) {
    int r = blockIdx.x;          // 0..7679, r = t*256+b
    int t = r >> 8, b = r & 255;
    bool act = t < declen[b];
    float lse = logf(rowsum[r]);
    float4* row = (float4*)(out + (size_t)b * PRED_B + (size_t)t * NV);
    for (int v4 = threadIdx.x; v4 < NV / 4; v4 += 256) {
        float4 x = row[v4];
        if (act) { x.x -= lse; x.y -= lse; x.z -= lse; x.w -= lse; }
        else     { x.x = 0.f; x.y = 0.f; x.z = 0.f; x.w = 0.f; }
        row[v4] = x;
    }
}

extern "C" void kernel_launch(void* const* d_in, const int* in_sizes, int n_in,
                              void* d_out, int out_size, void* d_ws, size_t ws_size,
                              hipStream_t stream) {
    const float* gimg  = (const float*)d_in[0];
    const int*   w_in  = (const int*)d_in[1];
    const int*   lens  = (const int*)d_in[2];
    const float* emb   = (const float*)d_in[3];
    const float* W_ih  = (const float*)d_in[4];
    const float* W_hh  = (const float*)d_in[5];
    const float* b_ih  = (const float*)d_in[6];
    const float* b_hh  = (const float*)d_in[7];
    const float* W_out = (const float*)d_in[8];
    const float* b_out = (const float*)d_in[9];
    float* out = (float*)d_out;

    char* p = (char*)d_ws;
    auto alloc = [&](size_t bytes) -> char* {
        char* r = p;
        p += (bytes + 255) & ~(size_t)255;
        return r;
    };
    int*   order   = (int*)alloc(NB * 4);
    int*   wsort   = (int*)alloc(NB * ML * 4);
    int*   declen  = (int*)alloc(NB * 4);
    int*   rowword = (int*)alloc(NT * NB * 4);
    float* g_s     = (float*)alloc((size_t)NB * NE * 4);
    float* gx      = (float*)alloc((size_t)NB * NG * 4);
    float* h       = (float*)alloc((size_t)NB * NH * 4);
    float* c       = (float*)alloc((size_t)NB * NH * 4);
    float* gates   = (float*)alloc((size_t)NB * NG * 4);
    float* rowsum  = (float*)alloc((size_t)NT * NB * 4);
    unsigned short* hb     = (unsigned short*)alloc((size_t)NB * NH * 2);
    unsigned short* h_allb = (unsigned short*)alloc((size_t)NT * NB * NH * 2);
    unsigned short* Whb    = (unsigned short*)alloc((size_t)NG * NH * 2);
    unsigned short* Wxb    = (unsigned short*)alloc((size_t)NG * NE * 2);
    unsigned short* Wob    = (unsigned short*)alloc((size_t)NV * NH * 2);
    unsigned short* embb   = (unsigned short*)alloc((size_t)NV * NE * 2);
    unsigned short* gallb  = (unsigned short*)alloc((size_t)NT * NB * NG * 2);

    sort_k<<<1, 256, 0, stream>>>(lens, order, declen, out + OFF_DEC);
    gather_k<<<NB, 256, 0, stream>>>(gimg, w_in, order, g_s, wsort, h, c, hb, out + OFF_TGT);
    rw_k<<<(NT * NB + 255) / 256, 256, 0, stream>>>(wsort, rowword);
    f2b_k<<<(NG * NH / 4 + 255) / 256, 256, 0, stream>>>(W_hh, Whb, NG * NH / 4);
    wxb_k<<<(NG * NE / 4 + 255) / 256, 256, 0, stream>>>(W_ih, Wxb);
    f2b_k<<<(NV * NH / 4 + 255) / 256, 256, 0, stream>>>(W_out, Wob, NV * NH / 4);
    f2b_k<<<(NV * NE / 4 + 255) / 256, 256, 0, stream>>>(emb, embb, NV * NE / 4);
    pad_k<<<(NB * NV + 255) / 256, 256, 0, stream>>>(out);
    zero_k<<<(NT * NB + 255) / 256, 256, 0, stream>>>(rowsum, NT * NB);

    // gx = g_s @ W_ih[:, :512]^T + b_ih + b_hh   (fp32, exact, once)
    gxgemm_k<<<dim3(NG / 64, NB / 64), 256, 0, stream>>>(g_s, W_ih, gx, b_ih, b_hh);

    // gallb[r] = bf16( emb[rowword[r]] @ Wxb^T )   (7680 x 2048, K=512)
    mfgemm<1, 0><<<dim3(NG / 128, NT * NB / 128), 256, 0, stream>>>(
        nullptr, rowword, embb, Wxb, NG,
        nullptr, nullptr, nullptr, nullptr, gallb, nullptr);

    for (int t = 0; t < NT; t++) {
        // gates = h @ Whb^T + gx + gallb[t]       (256 x 2048, K=512)
        mfgemm<0, 2><<<dim3(NG / 128, NB / 128), 256, 0, stream>>>(
            hb, nullptr, nullptr, Whb, NG,
            gx, gallb + (size_t)t * NB * NG, nullptr, gates, nullptr, nullptr);
        lstm_cell<<<(NB * NH) / 256, 256, 0, stream>>>(gates, h, c, hb, h_allb, declen, t);
    }

    // logits = h_allb @ Wob^T + b_out -> preds scatter + per-row sum(exp) atomics
    mfgemm<0, 1><<<dim3((NV + 127) / 128, NT * NB / 128), 256, 0, stream>>>(
        h_allb, nullptr, nullptr, Wob, NV,
        nullptr, nullptr, b_out, out, nullptr, rowsum);

    norm_k<<<NT * NB, 256, 0, stream>>>(out, rowsum, declen);
}

// Round 3
// 1407.249 us; speedup vs baseline: 3.0013x; 1.3660x over previous
//
#include <hip/hip_runtime.h>
#include <hip/hip_bf16.h>
#include <hip/hip_cooperative_groups.h>
#include <math.h>

namespace cg = cooperative_groups;

// Problem constants
#define NB   256      // batch
#define ML   31       // MAX_LEN
#define NT   30       // T = MAX_LEN-1 decode steps
#define NV   10000    // vocab
#define NH   512      // hidden
#define NE   512      // embed
#define NG   2048     // 4*H gates

// Output layout (floats): preds (256,31,10000) | target (256,30) | dec_len (256,)
#define OFF_TGT  (256LL*31LL*10000LL)
#define OFF_DEC  (OFF_TGT + 256LL*30LL)
#define PRED_B   (31LL*10000LL)

typedef __attribute__((ext_vector_type(8))) short bf16x8;
typedef __attribute__((ext_vector_type(4))) float f32x4;

__device__ inline unsigned short f2bf(float f) {
    unsigned int x = __float_as_uint(f);
    unsigned int r = x + 0x7FFFu + ((x >> 16) & 1u);   // RNE
    return (unsigned short)(r >> 16);
}
__device__ inline float bf2f(unsigned short u) {
    return __uint_as_float((unsigned int)u << 16);
}

// ---------- sort: stable descending argsort + per-step active counts ----------
__global__ void sort_k(const int* __restrict__ lens, int* __restrict__ order,
                       int* __restrict__ declen, int* __restrict__ cnt,
                       int* __restrict__ start, float* __restrict__ out_dec) {
    __shared__ int sd[NB];
    int i = threadIdx.x;
    int li = lens[i];
    int r = 0;
    for (int j = 0; j < NB; j++) {
        int lj = lens[j];
        r += (lj > li) || (lj == li && j < i);
    }
    order[r] = i;
    declen[r] = li - 1;
    out_dec[r] = (float)(li - 1);
    sd[r] = li - 1;
    __syncthreads();
    if (i < NT) {
        int c = 0;
        for (int b = 0; b < NB; b++) c += (sd[b] > i);
        cnt[i] = c;
    }
    __syncthreads();
    if (i == 0) {
        int s = 0;
        for (int t = 0; t < NT; t++) { start[t] = s; s += cnt[t]; }
        start[NT] = s;                 // n_active
    }
}

// ---------- gather sorted rows (bf16 image), zero hbuf, emit target -----------
__global__ void gather_k(const float* __restrict__ gimg, const int* __restrict__ w_in,
                         const int* __restrict__ order,
                         unsigned short* __restrict__ g_sb, int* __restrict__ wsort,
                         unsigned short* __restrict__ hbuf,
                         float* __restrict__ out_tgt) {
    int r = blockIdx.x, tid = threadIdx.x;
    int o = order[r];
    for (int e = tid; e < NE; e += 256) {
        g_sb[r * NE + e] = f2bf(gimg[o * NE + e]);
        hbuf[r * NH + e] = 0;
        hbuf[NB * NH + r * NH + e] = 0;
    }
    if (tid < ML) wsort[r * ML + tid] = w_in[o * ML + tid];
    if (tid < NT) out_tgt[r * NT + tid] = (float)w_in[o * ML + tid + 1];
}

// ---------- compact active-row lists ------------------------------------------
__global__ void rowlist_k(const int* __restrict__ wsort, const int* __restrict__ cnt,
                          const int* __restrict__ start,
                          int* __restrict__ rowlist, int* __restrict__ rowwc) {
    int t = blockIdx.x, b = threadIdx.x;
    if (b < cnt[t]) {
        int pos = start[t] + b;
        rowlist[pos] = t * 256 + b;
        rowwc[pos] = wsort[b * ML + t];
    }
}

// ---------- fp32 -> bf16 conversions ------------------------------------------
__global__ void f2b_k(const float* __restrict__ src, unsigned short* __restrict__ dst, int n4) {
    int i = blockIdx.x * 256 + threadIdx.x;
    if (i >= n4) return;
    float4 v = ((const float4*)src)[i];
    ushort4 o;
    o.x = f2bf(v.x); o.y = f2bf(v.y); o.z = f2bf(v.z); o.w = f2bf(v.w);
    ((ushort4*)dst)[i] = o;
}

// dst[j][k] = bf16(W_ih[j][koff+k]), j<2048, k<512
__global__ void wih_k(const float* __restrict__ W_ih, unsigned short* __restrict__ dst, int koff) {
    int gid = blockIdx.x * 256 + threadIdx.x;   // 2048*128 float4 chunks
    int j = gid >> 7, k4 = gid & 127;
    float4 v = *(const float4*)(W_ih + (size_t)j * (2 * NE) + koff + k4 * 4);
    ushort4 o;
    o.x = f2bf(v.x); o.y = f2bf(v.y); o.z = f2bf(v.z); o.w = f2bf(v.w);
    *(ushort4*)(dst + (size_t)j * NE + k4 * 4) = o;
}

// ---------- zero pad column preds[:,30,:] + zero scratch ----------------------
__global__ void pad_k(float* __restrict__ out) {
    int gid = blockIdx.x * 256 + threadIdx.x;
    if (gid < NB * NV) {
        int b = gid / NV, v = gid % NV;
        out[(size_t)b * PRED_B + (size_t)NT * NV + v] = 0.f;
    }
}
__global__ void zero_k(float* __restrict__ p, int n) {
    int i = blockIdx.x * 256 + threadIdx.x;
    if (i < n) p[i] = 0.f;
}

// ---------- bf16 MFMA GEMM, B-panel-in-LDS-once, A direct global --------------
// C(MxN) = A(MxK=512) @ B(NxK=512)^T.  Tile 128x128, 4 waves (2x2), wave 64x64.
// AMODE 0: A row m from Abf.  AMODE 1: A row m = Aemb + ridx[min(m,Mact-1)]*512.
// EPI 0: outb[m*N+n] = bf16(v)                 (masked m<Mact)
// EPI 1: preds scatter via rowlist + rowsum exp-atomics (masked)
// EPI 3: outf[m*N+n] = v + bias1[n] + bias2[n]
template <int AMODE, int EPI>
__launch_bounds__(256)
__global__ void bgemm(const unsigned short* __restrict__ Abf,
                      const int* __restrict__ ridx,
                      const unsigned short* __restrict__ Aemb,
                      const unsigned short* __restrict__ Bbf,
                      int N,
                      const int* __restrict__ mact_p,
                      const float* __restrict__ bias1,
                      const float* __restrict__ bias2,
                      const int* __restrict__ rowlist,
                      float* __restrict__ outf,
                      unsigned short* __restrict__ outb,
                      float* __restrict__ rowsum) {
    __shared__ __align__(16) char Bs[131072];   // [128][512] bf16, XOR-swizzled
    int Mact = mact_p ? *mact_p : (1 << 30);
    int m0 = blockIdx.y * 128;
    if (m0 >= Mact) return;
    int n0 = blockIdx.x * 128;
    int tid = threadIdx.x;
    int lane = tid & 63, w = tid >> 6;
    int wy = w >> 1, wx = w & 1;

    // stage full B panel once
#pragma unroll 4
    for (int p = 0; p < 32; ++p) {
        int row = (tid >> 6) + (p << 2);
        int bn = n0 + row; if (bn > N - 1) bn = N - 1;
        uint4 v = *(const uint4*)(Bbf + ((size_t)bn << 9) + ((tid & 63) << 3));
        int ba = (row << 10) + ((tid & 63) << 4); ba ^= (row & 7) << 4;
        *(uint4*)(Bs + ba) = v;
    }

    // A row pointers for this wave's 4 row-tiles
    const unsigned short* aptr[4];
#pragma unroll
    for (int rt = 0; rt < 4; ++rt) {
        int m = m0 + (wy << 6) + (rt << 4) + (lane & 15);
        if (AMODE == 0) aptr[rt] = Abf + ((size_t)m << 9);
        else {
            int mm = m < Mact ? m : (Mact - 1);
            aptr[rt] = Aemb + ((size_t)ridx[mm] << 9);
        }
    }

    f32x4 acc[4][4];
#pragma unroll
    for (int i = 0; i < 4; ++i)
#pragma unroll
        for (int j = 0; j < 4; ++j) acc[i][j] = (f32x4){0.f, 0.f, 0.f, 0.f};

    __syncthreads();

#pragma unroll 4
    for (int ks = 0; ks < 16; ++ks) {
        int koff = (ks << 5) + ((lane >> 4) << 3);
        bf16x8 bq[4];
#pragma unroll
        for (int ct = 0; ct < 4; ++ct) {
            int brow = (wx << 6) + (ct << 4) + (lane & 15);
            int bb = (brow << 10) + (koff << 1); bb ^= (brow & 7) << 4;
            bq[ct] = *(const bf16x8*)(Bs + bb);
        }
#pragma unroll
        for (int rt = 0; rt < 4; ++rt) {
            bf16x8 aq = *(const bf16x8*)(aptr[rt] + koff);
#pragma unroll
            for (int ct = 0; ct < 4; ++ct)
                acc[rt][ct] = __builtin_amdgcn_mfma_f32_16x16x32_bf16(aq, bq[ct], acc[rt][ct], 0, 0, 0);
        }
    }

    // epilogue; D frag: col = lane&15, row = (lane>>4)*4 + ri
#pragma unroll
    for (int rt = 0; rt < 4; ++rt) {
        float es4[4] = {0.f, 0.f, 0.f, 0.f};
#pragma unroll
        for (int ct = 0; ct < 4; ++ct) {
            int n = n0 + (wx << 6) + (ct << 4) + (lane & 15);
            bool okn = (n < N);
            float badd = 0.f;
            if (EPI == 3) badd = bias1[n] + bias2[n];
            else if (EPI == 1) badd = okn ? bias1[n] : 0.f;
#pragma unroll
            for (int ri = 0; ri < 4; ++ri) {
                int m = m0 + (wy << 6) + (rt << 4) + ((lane >> 4) << 2) + ri;
                float v = acc[rt][ct][ri] + badd;
                if (EPI == 3) {
                    outf[(size_t)m * N + n] = v;
                } else if (EPI == 0) {
                    if (m < Mact) outb[(size_t)m * N + n] = f2bf(v);
                } else {
                    if (okn && m < Mact) {
                        int r = rowlist[m];
                        outf[(size_t)(r & 255) * PRED_B + (size_t)(r >> 8) * NV + n] = v;
                        es4[ri] += __expf(v);
                    }
                }
            }
        }
        if (EPI == 1) {
#pragma unroll
            for (int ri = 0; ri < 4; ++ri) {
                float s = es4[ri];
                s += __shfl_xor(s, 1); s += __shfl_xor(s, 2);
                s += __shfl_xor(s, 4); s += __shfl_xor(s, 8);
                if ((lane & 15) == 0) {
                    int m = m0 + (wy << 6) + (rt << 4) + ((lane >> 4) << 2) + ri;
                    if (m < Mact) atomicAdd(&rowsum[m], s);
                }
            }
        }
    }
}

// ---------- cooperative fused LSTM recurrence ---------------------------------
// 64 blocks x 256 threads. Block g owns h-dims [g*8, g*8+8) = gate cols
// {q*512 + g*8 + j}. W_hh slice in LDS for all 30 steps; h ping-pong in global;
// c in registers; A-fragments direct global->VGPR.
__launch_bounds__(256)
__global__ void coop_lstm(unsigned short* __restrict__ hbuf,        // [2][256][512]
                          const unsigned short* __restrict__ Whb,   // [2048][512]
                          const float* __restrict__ gx,             // [256][2048]
                          const unsigned short* __restrict__ gallc, // [n_active][2048]
                          unsigned short* __restrict__ h_allc,      // [n_active][512]
                          const int* __restrict__ cnt,
                          const int* __restrict__ start) {
    cg::grid_group grid = cg::this_grid();
    __shared__ __align__(16) char BsM[32768];   // [32][512] bf16 swizzled
    __shared__ float Gs[256 * 33];              // gates scratch (pad 33)
    __shared__ float Gxs[256 * 33];             // gx slice (pad 33)
    int tid = threadIdx.x, g = blockIdx.x;
    int lane = tid & 63, w = tid >> 6;

    // load B panel once: local col c -> gate col (c>>3)*512 + g*8 + (c&7)
    {
        int lr = tid >> 3, ch8 = tid & 7;       // lr 0..31
        int gcol = (lr >> 3) * 512 + g * 8 + (lr & 7);
#pragma unroll
        for (int kp = 0; kp < 8; ++kp) {
            int chunk = ch8 + kp * 8;           // 0..63
            uint4 v = *(const uint4*)(Whb + ((size_t)gcol << 9) + (chunk << 3));
            int ba = (lr << 10) + (chunk << 4); ba ^= (lr & 7) << 4;
            *(uint4*)(BsM + ba) = v;
        }
    }
    // load gx slice once
    {
        int b = tid;
#pragma unroll
        for (int q = 0; q < 4; ++q) {
            float4 v0 = *(const float4*)(gx + (size_t)b * NG + q * 512 + g * 8);
            float4 v1 = *(const float4*)(gx + (size_t)b * NG + q * 512 + g * 8 + 4);
            float* dst = Gxs + b * 33 + q * 8;
            dst[0] = v0.x; dst[1] = v0.y; dst[2] = v0.z; dst[3] = v0.w;
            dst[4] = v1.x; dst[5] = v1.y; dst[6] = v1.z; dst[7] = v1.w;
        }
    }
    float creg[8];
#pragma unroll
    for (int j = 0; j < 8; ++j) creg[j] = 0.f;
    __syncthreads();

    for (int t = 0; t < NT; ++t) {
        int cnt_t = cnt[t];
        if (cnt_t > 0) {
            int st = start[t];
            const unsigned short* cur = hbuf + (size_t)(t & 1) * NB * NH;
            unsigned short* nxt = hbuf + (size_t)((t + 1) & 1) * NB * NH;

            // prefetch gallc row for elementwise phase
            uint4 gav[4];
            int b = tid;
            int pos = st + b;
            if (b < cnt_t) {
#pragma unroll
                for (int q = 0; q < 4; ++q)
                    gav[q] = *(const uint4*)(gallc + (size_t)pos * NG + q * 512 + g * 8);
            }

            f32x4 acc[4][2];
#pragma unroll
            for (int i = 0; i < 4; ++i) { acc[i][0] = (f32x4){0,0,0,0}; acc[i][1] = (f32x4){0,0,0,0}; }

#pragma unroll 4
            for (int ks = 0; ks < 16; ++ks) {
                int koff = (ks << 5) + ((lane >> 4) << 3);
                bf16x8 bq0, bq1;
                {
                    int brow = (lane & 15);
                    int bb = (brow << 10) + (koff << 1); bb ^= (brow & 7) << 4;
                    bq0 = *(const bf16x8*)(BsM + bb);
                    brow = 16 + (lane & 15);
                    bb = (brow << 10) + (koff << 1); bb ^= (brow & 7) << 4;
                    bq1 = *(const bf16x8*)(BsM + bb);
                }
#pragma unroll
                for (int rt = 0; rt < 4; ++rt) {
                    int rbase = (w << 6) + (rt << 4);
                    if (rbase < cnt_t) {
                        bf16x8 aq = *(const bf16x8*)(cur + ((size_t)(rbase + (lane & 15)) << 9) + koff);
                        acc[rt][0] = __builtin_amdgcn_mfma_f32_16x16x32_bf16(aq, bq0, acc[rt][0], 0, 0, 0);
                        acc[rt][1] = __builtin_amdgcn_mfma_f32_16x16x32_bf16(aq, bq1, acc[rt][1], 0, 0, 0);
                    }
                }
            }
            // write gates to LDS
#pragma unroll
            for (int rt = 0; rt < 4; ++rt) {
                int rbase = (w << 6) + (rt << 4);
                if (rbase < cnt_t) {
#pragma unroll
                    for (int ct = 0; ct < 2; ++ct)
#pragma unroll
                        for (int ri = 0; ri < 4; ++ri) {
                            int row = rbase + ((lane >> 4) << 2) + ri;
                            Gs[row * 33 + ct * 16 + (lane & 15)] = acc[rt][ct][ri];
                        }
                }
            }
            __syncthreads();
            // elementwise LSTM cell for owned h-dims
            if (b < cnt_t) {
                const unsigned short* gap = (const unsigned short*)gav;
                float hn8[8];
#pragma unroll
                for (int j = 0; j < 8; ++j) {
                    float ig = Gs[b * 33 + j]      + Gxs[b * 33 + j]      + bf2f(gap[j]);
                    float fg = Gs[b * 33 + 8 + j]  + Gxs[b * 33 + 8 + j]  + bf2f(gap[8 + j]);
                    float gg = Gs[b * 33 + 16 + j] + Gxs[b * 33 + 16 + j] + bf2f(gap[16 + j]);
                    float og = Gs[b * 33 + 24 + j] + Gxs[b * 33 + 24 + j] + bf2f(gap[24 + j]);
                    float i_ = 1.f / (1.f + __expf(-ig));
                    float f_ = 1.f / (1.f + __expf(-fg));
                    float o_ = 1.f / (1.f + __expf(-og));
                    float ea = __expf(-2.f * fabsf(gg));
                    float th = (1.f - ea) / (1.f + ea);
                    float g_ = (gg < 0.f) ? -th : th;
                    float cn = f_ * creg[j] + i_ * g_;
                    creg[j] = cn;
                    float ec = __expf(-2.f * fabsf(cn));
                    float tc = (1.f - ec) / (1.f + ec);
                    tc = (cn < 0.f) ? -tc : tc;
                    hn8[j] = o_ * tc;
                }
                __align__(16) unsigned short us[8];
#pragma unroll
                for (int j = 0; j < 8; ++j) us[j] = f2bf(hn8[j]);
                uint4 pv = *(const uint4*)us;
                *(uint4*)(nxt + (size_t)b * NH + g * 8) = pv;
                *(uint4*)(h_allc + (size_t)pos * NH + g * 8) = pv;
            }
            __threadfence();
            __syncthreads();   // Gs stable before next step's writes
        }
        grid.sync();
    }
}

// ---------- final pass: preds = logit - log(rowsum), zero inactive ------------
__global__ void norm_k(float* __restrict__ out, const float* __restrict__ rowsum,
                       const int* __restrict__ cnt, const int* __restrict__ start) {
    int r = blockIdx.x;          // 0..7679, r = t*256+b
    int t = r >> 8, b = r & 255;
    bool act = b < cnt[t];
    float lse = 0.f;
    if (act) lse = logf(rowsum[start[t] + b]);
    float4* row = (float4*)(out + (size_t)b * PRED_B + (size_t)t * NV);
    for (int v4 = threadIdx.x; v4 < NV / 4; v4 += 256) {
        float4 x;
        if (act) {
            x = row[v4];
            x.x -= lse; x.y -= lse; x.z -= lse; x.w -= lse;
        } else {
            x.x = 0.f; x.y = 0.f; x.z = 0.f; x.w = 0.f;
        }
        row[v4] = x;
    }
}

extern "C" void kernel_launch(void* const* d_in, const int* in_sizes, int n_in,
                              void* d_out, int out_size, void* d_ws, size_t ws_size,
                              hipStream_t stream) {
    const float* gimg  = (const float*)d_in[0];
    const int*   w_in  = (const int*)d_in[1];
    const int*   lens  = (const int*)d_in[2];
    const float* emb   = (const float*)d_in[3];
    const float* W_ih  = (const float*)d_in[4];
    const float* W_hh  = (const float*)d_in[5];
    const float* b_ih  = (const float*)d_in[6];
    const float* b_hh  = (const float*)d_in[7];
    const float* W_out = (const float*)d_in[8];
    const float* b_out = (const float*)d_in[9];
    float* out = (float*)d_out;

    char* p = (char*)d_ws;
    auto alloc = [&](size_t bytes) -> char* {
        char* r = p;
        p += (bytes + 255) & ~(size_t)255;
        return r;
    };
    int*   order   = (int*)alloc(NB * 4);
    int*   wsort   = (int*)alloc(NB * ML * 4);
    int*   declen  = (int*)alloc(NB * 4);
    int*   cnt     = (int*)alloc(NT * 4);
    int*   start   = (int*)alloc((NT + 1) * 4);
    int*   rowlist = (int*)alloc((size_t)NT * NB * 4);
    int*   rowwc   = (int*)alloc((size_t)NT * NB * 4);
    float* gx      = (float*)alloc((size_t)NB * NG * 4);
    float* rowsum  = (float*)alloc((size_t)NT * NB * 4);
    unsigned short* g_sb   = (unsigned short*)alloc((size_t)NB * NE * 2);
    unsigned short* hbuf   = (unsigned short*)alloc((size_t)2 * NB * NH * 2);
    unsigned short* h_allc = (unsigned short*)alloc((size_t)NT * NB * NH * 2);
    unsigned short* Whb    = (unsigned short*)alloc((size_t)NG * NH * 2);
    unsigned short* Wxl    = (unsigned short*)alloc((size_t)NG * NE * 2);
    unsigned short* Wxb    = (unsigned short*)alloc((size_t)NG * NE * 2);
    unsigned short* Wob    = (unsigned short*)alloc((size_t)NV * NH * 2);
    unsigned short* embb   = (unsigned short*)alloc((size_t)NV * NE * 2);
    unsigned short* gallc  = (unsigned short*)alloc((size_t)NT * NB * NG * 2);
    int* nact = start + NT;   // n_active lives at start[30]

    sort_k<<<1, 256, 0, stream>>>(lens, order, declen, cnt, start, out + OFF_DEC);
    gather_k<<<NB, 256, 0, stream>>>(gimg, w_in, order, g_sb, wsort, hbuf, out + OFF_TGT);
    rowlist_k<<<NT, 256, 0, stream>>>(wsort, cnt, start, rowlist, rowwc);
    f2b_k<<<(NG * NH / 4 + 255) / 256, 256, 0, stream>>>(W_hh, Whb, NG * NH / 4);
    wih_k<<<(NG * NE / 4 + 255) / 256, 256, 0, stream>>>(W_ih, Wxl, 0);
    wih_k<<<(NG * NE / 4 + 255) / 256, 256, 0, stream>>>(W_ih, Wxb, NE);
    f2b_k<<<(NV * NH / 4 + 255) / 256, 256, 0, stream>>>(W_out, Wob, NV * NH / 4);
    f2b_k<<<(NV * NE / 4 + 255) / 256, 256, 0, stream>>>(emb, embb, NV * NE / 4);
    pad_k<<<(NB * NV + 255) / 256, 256, 0, stream>>>(out);
    zero_k<<<(NT * NB + 255) / 256, 256, 0, stream>>>(rowsum, NT * NB);

    // gx = g_sb @ Wxl^T + b_ih + b_hh     (256 x 2048, K=512)
    bgemm<0, 3><<<dim3(NG / 128, NB / 128), 256, 0, stream>>>(
        g_sb, nullptr, nullptr, Wxl, NG, nullptr,
        b_ih, b_hh, nullptr, gx, nullptr, nullptr);

    // gallc[pos] = bf16( emb[rowwc[pos]] @ Wxb^T )   (n_active x 2048, K=512)
    bgemm<1, 0><<<dim3(NG / 128, NT * NB / 128), 256, 0, stream>>>(
        nullptr, rowwc, embb, Wxb, NG, nact,
        nullptr, nullptr, nullptr, nullptr, gallc, nullptr);

    // fused 30-step recurrence (cooperative)
    {
        void* cargs[] = { (void*)&hbuf, (void*)&Whb, (void*)&gx, (void*)&gallc,
                          (void*)&h_allc, (void*)&cnt, (void*)&start };
        hipLaunchCooperativeKernel((void*)coop_lstm, dim3(64), dim3(256), cargs, 0, stream);
    }

    // logits = h_allc @ Wob^T + b_out -> preds scatter + rowsum exp-atomics
    bgemm<0, 1><<<dim3((NV + 127) / 128, NT * NB / 128), 256, 0, stream>>>(
        h_allc, nullptr, nullptr, Wob, NV, nact,
        b_out, nullptr, rowlist, out, nullptr, rowsum);

    norm_k<<<NT * NB, 256, 0, stream>>>(out, rowsum, cnt, start);
}